// Round 2
// baseline (237.178 us; speedup 1.0000x reference)
//
#include <hip/hip_runtime.h>
#include <math.h>

// GaussianAdjacencyMatrix: out[b,i,j] = m*exp(-||x_i-x_j||^2/sigma^2) / (row_sum + 1e-8)
// B=8, N=2048, D=3.
// Structure: ONE WAVE PER ROW. 64 lanes x 32 j's each = 2048 columns.
//  - No LDS, no __syncthreads(): row sum is a 6-step shfl_xor butterfly.
//  - Coords for 4 consecutive j's are exactly 3 float4s (48 B) -> consecutive
//    lanes read consecutive 48-B chunks: coalesced, L1/L2-resident (24 KiB/batch).
//  - Mask loads / out stores are nontemporal (streamed once, keep L2 for coords).
//  - 8 independent 1-KiB mask loads in flight per wave -> deep MLP, no barriers.

#define NN      2048
#define THREADS 256
#define WPB     4           // waves (rows) per block
#define EPS     1e-8f

// clang ext-vector type: __builtin_nontemporal_* requires a native vector,
// not HIP_vector_type<float,4> (a struct).
typedef float vfloat4 __attribute__((ext_vector_type(4)));

__global__ __launch_bounds__(THREADS) void gauss_adj_kernel(
    const float* __restrict__ coords,   // [B, N, 3]
    const float* __restrict__ masks,    // [B, N, N]
    const float* __restrict__ sigma,    // [1]
    float* __restrict__ out)            // [B, N, N]
{
    const int row  = blockIdx.x * WPB + (threadIdx.x >> 6);  // b*N + i
    const int lane = threadIdx.x & 63;
    const int b    = row >> 11;          // / 2048
    const int i    = row & (NN - 1);

    const float* cb = coords + (size_t)b * NN * 3;
    const float xi = cb[i * 3 + 0];
    const float yi = cb[i * 3 + 1];
    const float zi = cb[i * 3 + 2];
    const float s  = sigma[0];
    const float inv_s2 = 1.0f / (s * s);

    const vfloat4* mrow = (const vfloat4*)(masks + (size_t)row * NN);
    vfloat4*       orow = (vfloat4*)(out + (size_t)row * NN);
    const float4*  c4   = (const float4*)cb;   // 3 float4s per 4 columns

    vfloat4 a[8];
    float lsum = 0.0f;

    #pragma unroll
    for (int w = 0; w < 8; ++w) {
        const int q = w * 64 + lane;                 // float4 column index 0..511
        const vfloat4 m = __builtin_nontemporal_load(&mrow[q]);
        const float4 c0 = c4[3 * q + 0];
        const float4 c1 = c4[3 * q + 1];
        const float4 c2 = c4[3 * q + 2];

        float dx, dy, dz, d;
        dx = xi - c0.x; dy = yi - c0.y; dz = zi - c0.z;
        d  = dx * dx + dy * dy + dz * dz;
        const float a0 = __expf(-d * inv_s2) * m.x;

        dx = xi - c0.w; dy = yi - c1.x; dz = zi - c1.y;
        d  = dx * dx + dy * dy + dz * dz;
        const float a1 = __expf(-d * inv_s2) * m.y;

        dx = xi - c1.z; dy = yi - c1.w; dz = zi - c2.x;
        d  = dx * dx + dy * dy + dz * dz;
        const float a2 = __expf(-d * inv_s2) * m.z;

        dx = xi - c2.y; dy = yi - c2.z; dz = zi - c2.w;
        d  = dx * dx + dy * dy + dz * dz;
        const float a3 = __expf(-d * inv_s2) * m.w;

        vfloat4 av;
        av.x = a0; av.y = a1; av.z = a2; av.w = a3;
        a[w] = av;
        lsum += (a0 + a1) + (a2 + a3);
    }

    // full-wave butterfly: every lane ends with the row total
    #pragma unroll
    for (int off = 32; off > 0; off >>= 1)
        lsum += __shfl_xor(lsum, off, 64);

    const float inv = 1.0f / (lsum + EPS);

    #pragma unroll
    for (int w = 0; w < 8; ++w) {
        const int q = w * 64 + lane;
        vfloat4 o = a[w];
        o.x *= inv; o.y *= inv; o.z *= inv; o.w *= inv;
        __builtin_nontemporal_store(o, &orow[q]);
    }
}

extern "C" void kernel_launch(void* const* d_in, const int* in_sizes, int n_in,
                              void* d_out, int out_size, void* d_ws, size_t ws_size,
                              hipStream_t stream) {
    const float* coords = (const float*)d_in[0];   // [B,N,3]
    const float* masks  = (const float*)d_in[1];   // [B,N,N]
    const float* sigma  = (const float*)d_in[2];   // [1]
    float* out = (float*)d_out;

    const int B    = in_sizes[0] / (NN * 3);
    const int rows = B * NN;
    gauss_adj_kernel<<<rows / WPB, THREADS, 0, stream>>>(coords, masks, sigma, out);
}